// Round 2
// baseline (233.201 us; speedup 1.0000x reference)
//
#include <hip/hip_runtime.h>
#include <math.h>

// TopK router: logits = x @ W^T (fp32), top-2 per token + softmax over the 2.
// x: [nTok, D] fp32, W: [E=64, D] fp32.
// out: [probs (nTok*2 f32)] ++ [idx (nTok*2, written as f32 values)]
//
// Structure: 1 block (1024 thr = 16 waves) per 64-token group.
//   wave = (expert-quarter q = wid&3, K-slice s = wid>>2)
//   lane = token; acc[16] experts; W loads are wave-uniform -> s_load (SGPR
//   broadcast), x staged global->reg->LDS per K-slice chunk.
//   K-partials reduced across slice waves via 3 deterministic LDS rounds.

#define TOK 64        // tokens per block (= wave width, lane = token)
#define BK 32         // k per staged chunk
#define LDK 36        // padded LDS stride (stride-36 floats: conflict-free b128)
#define THREADS 1024
#define NSLICE 4      // K-split across waves
#define EPW 16        // experts per wave

__global__ __launch_bounds__(THREADS, 4)
void router_main(const float* __restrict__ x, const float* __restrict__ W,
                 float* __restrict__ out_probs, float* __restrict__ out_idx,
                 int D) {
  __shared__ float As[NSLICE][TOK][LDK];   // x chunks, one per K-slice group
  __shared__ float Sl[4][TOK][20];         // reduction buffer (one round)

  const int tid  = threadIdx.x;
  const int wid  = __builtin_amdgcn_readfirstlane((int)(tid >> 6));
  const int lane = tid & 63;               // token within group
  const int q    = wid & 3;                // expert quarter -> experts q*16..+15
  const int s    = wid >> 2;               // K-slice
  const int m0   = blockIdx.x * TOK;

  const int Ks      = D >> 2;              // 1024: k per slice
  const int kbase   = s * Ks;
  const int nChunks = Ks / BK;             // 32

  // staging map: slice-group = 4 waves = 256 threads; chunk = 64 rows x 8 f4
  const int ts = tid & 255;
  const int r0 = ts >> 3,          c0 = ts & 7;
  const int r1 = (ts + 256) >> 3,  c1 = (ts + 256) & 7;

  float acc[EPW];
#pragma unroll
  for (int j = 0; j < EPW; ++j) acc[j] = 0.f;

  const float* xg = x + (size_t)m0 * D + kbase;

  // prologue: stage chunk 0
  {
    const float4 a = *(const float4*)(xg + (size_t)r0 * D + c0 * 4);
    const float4 b = *(const float4*)(xg + (size_t)r1 * D + c1 * 4);
    *(float4*)&As[s][r0][c0 * 4] = a;
    *(float4*)&As[s][r1][c1 * 4] = b;
  }
  __syncthreads();

  for (int c = 0; c < nChunks; ++c) {
    // issue next chunk's global loads early (latency hides under compute)
    float4 pa, pb;
    const bool more = (c + 1 < nChunks);
    if (more) {
      const float* xn = xg + (size_t)(c + 1) * BK;
      pa = *(const float4*)(xn + (size_t)r0 * D + c0 * 4);
      pb = *(const float4*)(xn + (size_t)r1 * D + c1 * 4);
    }

    // compute: 32 k x 16 experts = 512 FMAs per lane per chunk.
    // W address is wave-uniform -> scalar loads (SGPR broadcast).
    const float* wb = W + (size_t)(q * EPW) * D + (kbase + c * BK);
#pragma unroll
    for (int kk = 0; kk < BK / 4; ++kk) {
      const float4 xv = *(const float4*)&As[s][lane][kk * 4];
#pragma unroll
      for (int j = 0; j < EPW; ++j) {
        const float4 wv = *(const float4*)(wb + (size_t)j * D + kk * 4);
        acc[j] = fmaf(xv.x, wv.x, acc[j]);
        acc[j] = fmaf(xv.y, wv.y, acc[j]);
        acc[j] = fmaf(xv.z, wv.z, acc[j]);
        acc[j] = fmaf(xv.w, wv.w, acc[j]);
      }
    }
    __syncthreads();                        // everyone done reading As[s]
    if (more) {
      *(float4*)&As[s][r0][c0 * 4] = pa;
      *(float4*)&As[s][r1][c1 * 4] = pb;
    }
    __syncthreads();                        // next chunk published
  }

  // ---- deterministic K-slice reduction into slice 0 (3 rounds) ----
  for (int r = 1; r < NSLICE; ++r) {
    if (s == r) {
#pragma unroll
      for (int j4 = 0; j4 < EPW; j4 += 4)
        *(float4*)&Sl[q][lane][j4] =
            make_float4(acc[j4], acc[j4 + 1], acc[j4 + 2], acc[j4 + 3]);
    }
    __syncthreads();
    if (s == 0) {
#pragma unroll
      for (int j = 0; j < EPW; ++j) acc[j] += Sl[q][lane][j];
    }
    __syncthreads();
  }

  // ---- gather full logits row per token (reuse As memory), stride 68 ----
  float* Sl2 = &As[0][0][0];                // [64][68] fits in As (9216 floats)
  if (s == 0) {
#pragma unroll
    for (int j4 = 0; j4 < EPW; j4 += 4)
      *(float4*)&Sl2[lane * 68 + q * EPW + j4] =
          make_float4(acc[j4], acc[j4 + 1], acc[j4 + 2], acc[j4 + 3]);
  }
  __syncthreads();

  // ---- top-2 + softmax: one thread per token ----
  // Strict '>' keeps the lowest index on ties (jax.lax.top_k semantics).
  if (tid < TOK) {
    float b0 = -INFINITY, b1 = -INFINITY;
    int i0 = 0, i1 = 0;
    const float* row = &Sl2[tid * 68];
#pragma unroll
    for (int e4 = 0; e4 < 16; ++e4) {
      const float4 v = *(const float4*)(row + e4 * 4);
      const float vv[4] = {v.x, v.y, v.z, v.w};
#pragma unroll
      for (int u = 0; u < 4; ++u) {
        const float val = vv[u];
        const int e = e4 * 4 + u;
        if (val > b0) {
          b1 = b0; i1 = i0;
          b0 = val; i0 = e;
        } else if (val > b1) {
          b1 = val; i1 = e;
        }
      }
    }
    const float e1  = expf(b1 - b0);        // <= 1
    const float inv = 1.f / (1.f + e1);
    const int t = m0 + tid;
    out_probs[t * 2 + 0] = inv;
    out_probs[t * 2 + 1] = e1 * inv;
    out_idx[t * 2 + 0] = (float)i0;
    out_idx[t * 2 + 1] = (float)i1;
  }
}

extern "C" void kernel_launch(void* const* d_in, const int* in_sizes, int n_in,
                              void* d_out, int out_size, void* d_ws, size_t ws_size,
                              hipStream_t stream) {
  const float* x = (const float*)d_in[0];
  const float* W = (const float*)d_in[1];

  const int E = 64;
  const int D = in_sizes[1] / E;            // 4096
  const int nTok = in_sizes[0] / D;         // 16384

  float* probs = (float*)d_out;                       // nTok*2 floats
  float* idxo  = (float*)d_out + (size_t)nTok * 2;    // nTok*2 "float" indices

  dim3 grid(nTok / TOK), block(THREADS);
  hipLaunchKernelGGL(router_main, grid, block, 0, stream,
                     x, W, probs, idxo, D);
}